// Round 6
// baseline (262.233 us; speedup 1.0000x reference)
//
#include <hip/hip_runtime.h>

// VectorQuantizer: latents (16,128,64,64) f32, codebook (1024,128) f32.
// out[b,d,h,w] = codebook[argmin_k fl(fl(x2 - 2*dot(x,e_k)) + e2_k)][d]
//
// MFMA bf16 scoring + exact fp32 rescue, register-fit partition:
//  block = 256 thr / 4 waves, 64 px, 1024 codes.
//  wave w: px-half (w>>1)*32..+32, code-half (w&1)*512..+512.
//  A = 8 frags (32 VGPRs) built straight from global; B ping-pong streamed
//  bf16 from L2 (4 loads : 8 MFMAs); per-iter branchy candidate collect.
//  pre-pass: 4 c-iters/wave -> ub over 128 codes/px; thr = ub + 2M,
//  M = 2e-4*sqrt(x2)+1.5e-4 (Cauchy-Schwarz bf16 bound, e2max<=128/1024^2).
//  True argmin always collected; overflow -> exact-min re-sweep fallback.
//  rescue: exact fp32 serial ascending-d fmaf chain (validated rounds 1-5),
//  lex (t3,k) u64 atomicMin -> np first-index tie-break (t3>0).
// Round-2 lesson: codebook never via SMEM path. Round-5 lesson: per-wave
// working set must fit in registers (64px A-set spilled at VGPR=84).

typedef __attribute__((ext_vector_type(8))) short short8;
typedef __attribute__((ext_vector_type(4))) float f32x4;

#define VQ_D 128
#define VQ_K 1024
#define VQ_HW 4096
#define CAND_CAP 1536

__device__ inline unsigned short f2bf(float f) {   // RNE fp32->bf16
    unsigned u = __float_as_uint(f);
    return (unsigned short)((u + 0x7FFFu + ((u >> 16) & 1u)) >> 16);
}

__global__ __launch_bounds__(128)
void vq_prep_kernel(const float* __restrict__ cb, unsigned short* __restrict__ cbbf,
                    float* __restrict__ e2) {
    const int k = blockIdx.x * 128 + threadIdx.x;
    const float* crow = cb + (size_t)k * VQ_D;
    unsigned short* brow = cbbf + (size_t)k * VQ_D;
    float s = 0.f;
    #pragma unroll
    for (int d = 0; d < VQ_D; ++d) {
        const float v = crow[d];
        s = fmaf(v, v, s);          // serial chain (rounds 1-5 validated)
        brow[d] = f2bf(v);
    }
    e2[k] = s;
}

__global__ __launch_bounds__(256, 3)
void vq_main_kernel(const float* __restrict__ latents,
                    const float* __restrict__ cb,
                    const unsigned short* __restrict__ cbbf,
                    const float* __restrict__ e2g,
                    float* __restrict__ out) {
    __shared__ __align__(16) float xl[VQ_D * 64];   // [d][px], 32 KB
    __shared__ unsigned int cand[CAND_CAP];         // 6 KB
    __shared__ float pmins[4][32];
    __shared__ float threshs[64];
    __shared__ float x2s[64];
    __shared__ unsigned long long fkey[64];
    __shared__ int ncand;

    const int tid  = threadIdx.x;
    const int lane = tid & 63;
    const int wave = __builtin_amdgcn_readfirstlane(tid >> 6);
    const int quad = lane >> 4;
    const int mm   = lane & 15;
    const int blk  = blockIdx.x;
    const int b    = blk >> 6;
    const int hw0  = (blk & 63) << 6;

    const int pxb = (wave >> 1) << 5;   // px half base: 0 / 32
    const int cs  = (wave & 1) << 9;    // code half base: 0 / 512

    const float* xg = latents + (size_t)b * VQ_D * VQ_HW + hw0;

    // ---- stage x-tile d-major (conflict-free b128 writes) ----
    {
        const int px4 = (tid & 15) << 2;
        const int d0  = (tid >> 4) << 3;
        #pragma unroll
        for (int i = 0; i < 8; ++i) {
            const int d = d0 + i;
            *(float4*)(xl + d * 64 + px4) =
                *(const float4*)(xg + (size_t)d * VQ_HW + px4);
        }
    }
    if (tid == 0) ncand = 0;
    if (tid < 64) fkey[tid] = ~0ULL;

    // ---- A-frags direct from global (64B-segment coalesced, L1-hot) ----
    // px = pxb + p*16 + mm, d = t*32 + quad*8 + j
    short8 A[2][4];
    #pragma unroll
    for (int p = 0; p < 2; ++p) {
        #pragma unroll
        for (int t = 0; t < 4; ++t) {
            const float* src =
                xg + (size_t)(t * 32 + quad * 8) * VQ_HW + pxb + p * 16 + mm;
            short8 a;
            #pragma unroll
            for (int j = 0; j < 8; ++j)
                a[j] = (short)f2bf(src[(size_t)j * VQ_HW]);
            A[p][t] = a;
        }
    }
    __syncthreads();

    // ---- x2 per px: exact serial ascending-d chain ----
    float x2 = 0.f;
    if (tid < 64) {
        #pragma unroll
        for (int d = 0; d < VQ_D; ++d) {
            const float v = xl[d * 64 + tid];
            x2 = fmaf(v, v, x2);
        }
        x2s[tid] = x2;
    }

    const unsigned short* bbase = cbbf + (size_t)(cs + mm) * VQ_D + quad * 8;

    auto loadB = [&](short8* Bt, int c) {
        #pragma unroll
        for (int t = 0; t < 4; ++t)
            Bt[t] = *(const short8*)(bbase + (size_t)c * 16 * VQ_D + t * 32);
    };

    // ---- pre-pass: 4 c-iters -> per-px min over this wave's 64 codes ----
    float bmin[8];
    #pragma unroll
    for (int i = 0; i < 8; ++i) bmin[i] = 1e30f;

    #pragma unroll 1
    for (int c = 0; c < 4; ++c) {
        short8 B[4];
        loadB(B, c);
        f32x4 C[2] = {{0.f,0.f,0.f,0.f},{0.f,0.f,0.f,0.f}};
        #pragma unroll
        for (int t = 0; t < 4; ++t) {
            C[0] = __builtin_amdgcn_mfma_f32_16x16x32_bf16(A[0][t], B[t], C[0], 0, 0, 0);
            C[1] = __builtin_amdgcn_mfma_f32_16x16x32_bf16(A[1][t], B[t], C[1], 0, 0, 0);
        }
        const float e2c = e2g[cs + c * 16 + mm];
        #pragma unroll
        for (int p = 0; p < 2; ++p)
            #pragma unroll
            for (int r = 0; r < 4; ++r)
                bmin[p * 4 + r] = fminf(bmin[p * 4 + r], fmaf(-2.0f, C[p][r], e2c));
    }
    #pragma unroll
    for (int i = 0; i < 8; ++i) {
        float v = bmin[i];
        v = fminf(v, __shfl_xor(v, 1));
        v = fminf(v, __shfl_xor(v, 2));
        v = fminf(v, __shfl_xor(v, 4));
        v = fminf(v, __shfl_xor(v, 8));
        bmin[i] = v;
    }
    if (mm == 0) {
        #pragma unroll
        for (int p = 0; p < 2; ++p)
            #pragma unroll
            for (int r = 0; r < 4; ++r)
                pmins[wave][p * 16 + quad * 4 + r] = bmin[p * 4 + r];
    }
    __syncthreads();
    if (tid < 64) {
        const int h = tid >> 5, i = tid & 31;
        const float ub = fminf(pmins[2 * h][i], pmins[2 * h + 1][i]);
        const float M = 2.0e-4f * sqrtf(x2) + 1.5e-4f;
        threshs[tid] = ub + 2.0f * M;
    }
    __syncthreads();

    float thr[8];
    #pragma unroll
    for (int p = 0; p < 2; ++p)
        #pragma unroll
        for (int r = 0; r < 4; ++r)
            thr[p * 4 + r] = threshs[pxb + p * 16 + quad * 4 + r];

    float rmin[8];
    #pragma unroll
    for (int i = 0; i < 8; ++i) rmin[i] = 1e30f;

    auto process = [&](const short8* Bt, int c) {
        const float e2c = e2g[cs + c * 16 + mm];   // issue early
        f32x4 C[2] = {{0.f,0.f,0.f,0.f},{0.f,0.f,0.f,0.f}};
        #pragma unroll
        for (int t = 0; t < 4; ++t) {
            C[0] = __builtin_amdgcn_mfma_f32_16x16x32_bf16(A[0][t], Bt[t], C[0], 0, 0, 0);
            C[1] = __builtin_amdgcn_mfma_f32_16x16x32_bf16(A[1][t], Bt[t], C[1], 0, 0, 0);
        }
        const int code = cs + c * 16 + mm;
        #pragma unroll
        for (int p = 0; p < 2; ++p)
            #pragma unroll
            for (int r = 0; r < 4; ++r) {
                const float s = fmaf(-2.0f, C[p][r], e2c);
                rmin[p * 4 + r] = fminf(rmin[p * 4 + r], s);
                if (s <= thr[p * 4 + r]) {
                    const int idx = atomicAdd(&ncand, 1);
                    if (idx < CAND_CAP) {
                        const int px = pxb + p * 16 + quad * 4 + r;
                        cand[idx] = ((unsigned)px << 16) | (unsigned)code;
                    }
                }
            }
    };

    // ---- main sweep: 32 c-iters, ping-pong B (no register copies) ----
    short8 Ba[4], Bb[4];
    loadB(Ba, 0);
    #pragma unroll 1
    for (int c = 0; c < 32; c += 2) {
        loadB(Bb, c + 1);
        process(Ba, c);
        if (c + 2 < 32) loadB(Ba, c + 2);
        process(Bb, c + 1);
    }
    __syncthreads();

    int nc = ncand;
    if (nc > CAND_CAP) {
        // Fallback (essentially never): tight threshold from exact bf16 min.
        #pragma unroll
        for (int i = 0; i < 8; ++i) {
            float v = rmin[i];
            v = fminf(v, __shfl_xor(v, 1));
            v = fminf(v, __shfl_xor(v, 2));
            v = fminf(v, __shfl_xor(v, 4));
            v = fminf(v, __shfl_xor(v, 8));
            rmin[i] = v;
        }
        if (mm == 0) {
            #pragma unroll
            for (int p = 0; p < 2; ++p)
                #pragma unroll
                for (int r = 0; r < 4; ++r)
                    pmins[wave][p * 16 + quad * 4 + r] = rmin[p * 4 + r];
        }
        __syncthreads();
        if (tid == 0) ncand = 0;
        if (tid < 64) {
            const int h = tid >> 5, i = tid & 31;
            const float mn = fminf(pmins[2 * h][i], pmins[2 * h + 1][i]);
            const float M = 2.0e-4f * sqrtf(x2) + 1.5e-4f;
            threshs[tid] = mn + 2.0f * M;
        }
        __syncthreads();
        #pragma unroll
        for (int p = 0; p < 2; ++p)
            #pragma unroll
            for (int r = 0; r < 4; ++r)
                thr[p * 4 + r] = threshs[pxb + p * 16 + quad * 4 + r];

        #pragma unroll 1
        for (int c = 0; c < 32; ++c) {
            short8 B[4];
            loadB(B, c);
            f32x4 C[2] = {{0.f,0.f,0.f,0.f},{0.f,0.f,0.f,0.f}};
            #pragma unroll
            for (int t = 0; t < 4; ++t) {
                C[0] = __builtin_amdgcn_mfma_f32_16x16x32_bf16(A[0][t], B[t], C[0], 0, 0, 0);
                C[1] = __builtin_amdgcn_mfma_f32_16x16x32_bf16(A[1][t], B[t], C[1], 0, 0, 0);
            }
            const float e2c = e2g[cs + c * 16 + mm];
            const int code = cs + c * 16 + mm;
            #pragma unroll
            for (int p = 0; p < 2; ++p)
                #pragma unroll
                for (int r = 0; r < 4; ++r) {
                    const float s = fmaf(-2.0f, C[p][r], e2c);
                    if (s <= thr[p * 4 + r]) {
                        const int idx = atomicAdd(&ncand, 1);
                        if (idx < CAND_CAP) {
                            const int px = pxb + p * 16 + quad * 4 + r;
                            cand[idx] = ((unsigned)px << 16) | (unsigned)code;
                        }
                    }
                }
        }
        __syncthreads();
        nc = ncand;
        if (nc > CAND_CAP) nc = CAND_CAP;   // absolute safety
    }

    // ---- rescue: exact fp32 serial ascending-d chain per candidate ----
    for (int i = tid; i < nc; i += 256) {
        const unsigned pc = cand[i];
        const int px = (int)(pc >> 16);
        const int k  = (int)(pc & 0xFFFFu);
        const float* crow = cb + (size_t)k * VQ_D;
        float dot = 0.f;
        #pragma unroll
        for (int q = 0; q < 32; ++q) {
            const float4 cv = *(const float4*)(crow + q * 4);
            dot = fmaf(xl[(q * 4 + 0) * 64 + px], cv.x, dot);
            dot = fmaf(xl[(q * 4 + 1) * 64 + px], cv.y, dot);
            dot = fmaf(xl[(q * 4 + 2) * 64 + px], cv.z, dot);
            dot = fmaf(xl[(q * 4 + 3) * 64 + px], cv.w, dot);
        }
        const float t3 = (x2s[px] - 2.0f * dot) + e2g[k];
        const unsigned long long key =
            ((unsigned long long)__float_as_uint(t3) << 32) | (unsigned)k;
        atomicMin(&fkey[px], key);
    }
    __syncthreads();

    // ---- writeback ----
    {
        const int px = tid & 63;
        const int dh = tid >> 6;
        const int fb = (int)(fkey[px] & 0xFFFFFFFFULL);
        const float* crow = cb + (size_t)fb * VQ_D;
        float* og = out + (size_t)b * VQ_D * VQ_HW + hw0;
        #pragma unroll
        for (int i = 0; i < 32; ++i) {
            const int d = dh * 32 + i;
            og[(size_t)d * VQ_HW + px] = crow[d];
        }
    }
}

extern "C" void kernel_launch(void* const* d_in, const int* in_sizes, int n_in,
                              void* d_out, int out_size, void* d_ws, size_t ws_size,
                              hipStream_t stream) {
    const float* latents = (const float*)d_in[0];
    const float* cb      = (const float*)d_in[1];
    unsigned short* cbbf = (unsigned short*)d_ws;              // 256 KB
    float* e2            = (float*)((char*)d_ws + 262144);     // 4 KB
    float* out           = (float*)d_out;

    vq_prep_kernel<<<dim3(8), dim3(128), 0, stream>>>(cb, cbbf, e2);
    vq_main_kernel<<<dim3(1024), dim3(256), 0, stream>>>(latents, cb, cbbf, e2, out);
}